// Round 1
// baseline (140.067 us; speedup 1.0000x reference)
//
#include <hip/hip_runtime.h>
#include <math.h>

// Problem constants
#define QDIM 512     // 2^9 state dim
#define DD   128     // K*C_IN = input dim of quadratic form
#define LIN  4096
#define LOUT 4089    // (4096 - 7 - 1)/1 + 1
#define NC   16      // C_IN
#define NB   16      // batch

// ---------------------------------------------------------------------------
// Precompute: A = (E*R3*E*R2*E*R1)[:, :128], then Q = A^T S A  (S=diag(+-1))
// B buffers are 512x128 row-major [state i][col j].
// ---------------------------------------------------------------------------

__global__ void init_B(float* __restrict__ B) {
  int e = blockIdx.x * 256 + threadIdx.x;
  if (e < QDIM * DD) {
    int row = e / DD, col = e % DD;
    B[e] = (row == col) ? 1.0f : 0.0f;
  }
}

// Apply RY layer l (9 qubits) to each column of B, in place.
// One block per column j; 256 threads = 256 butterfly pairs per qubit.
__global__ void ry_kernel(float* __restrict__ B, const float* __restrict__ theta, int l) {
  __shared__ float col[QDIM];
  int j = blockIdx.x;
  int p = threadIdx.x;              // 0..255
  col[p]       = B[p * DD + j];
  col[p + 256] = B[(p + 256) * DD + j];
  __syncthreads();
  #pragma unroll
  for (int q = 0; q < 9; ++q) {
    float half = theta[l * 9 + q] * 0.5f;
    float c = cosf(half), s = sinf(half);
    int right = QDIM >> (q + 1);    // 256 >> q
    int a = p >> (8 - q);
    int r = p & (right - 1);
    int i0 = (a * 2) * right + r;
    int i1 = i0 + right;
    // pairs (i0,i1) partition [0,512) across threads -> no intra-step hazard
    float v0 = col[i0], v1 = col[i1];
    col[i0] = c * v0 - s * v1;
    col[i1] = s * v0 + c * v1;
    __syncthreads();
  }
  B[p * DD + j]         = col[p];
  B[(p + 256) * DD + j] = col[p + 256];
}

// C = E (512x512) * B (512x128). One block per output row i, 128 threads (cols).
__global__ void mm_kernel(const float* __restrict__ E, const float* __restrict__ B,
                          float* __restrict__ C) {
  __shared__ float erow[QDIM];
  int i = blockIdx.x;
  int tid = threadIdx.x;            // 128
  for (int m = tid; m < QDIM; m += 128) erow[m] = E[i * QDIM + m];
  __syncthreads();
  int j = tid;
  float a0 = 0.f, a1 = 0.f, a2 = 0.f, a3 = 0.f;
  #pragma unroll 4
  for (int m = 0; m < QDIM; m += 4) {
    a0 = fmaf(erow[m + 0], B[(m + 0) * DD + j], a0);
    a1 = fmaf(erow[m + 1], B[(m + 1) * DD + j], a1);
    a2 = fmaf(erow[m + 2], B[(m + 2) * DD + j], a2);
    a3 = fmaf(erow[m + 3], B[(m + 3) * DD + j], a3);
  }
  C[i * DD + j] = (a0 + a1) + (a2 + a3);
}

// Q[j1][j2] = sum_i sgn(i) A[i][j1] A[i][j2];  sgn = +1 (i<256), -1 (i>=256)
__global__ void formq_kernel(const float* __restrict__ A, float* __restrict__ Q) {
  __shared__ float colA[QDIM];
  int j1 = blockIdx.x;
  int tid = threadIdx.x;            // 128
  for (int i = tid; i < QDIM; i += 128) {
    float sgn = (i < 256) ? 1.0f : -1.0f;
    colA[i] = sgn * A[i * DD + j1];
  }
  __syncthreads();
  int j2 = tid;
  float a0 = 0.f, a1 = 0.f, a2 = 0.f, a3 = 0.f;
  #pragma unroll 4
  for (int i = 0; i < QDIM; i += 4) {
    a0 = fmaf(colA[i + 0], A[(i + 0) * DD + j2], a0);
    a1 = fmaf(colA[i + 1], A[(i + 1) * DD + j2], a1);
    a2 = fmaf(colA[i + 2], A[(i + 2) * DD + j2], a2);
    a3 = fmaf(colA[i + 3], A[(i + 3) * DD + j2], a3);
  }
  Q[j1 * DD + j2] = (a0 + a1) + (a2 + a3);
}

// ---------------------------------------------------------------------------
// Main pass: out[b,t] = v^T Q v / (v^T v + 1e-12),  v[c*8+k] = x[b,c,t+k]
// One thread per output t; x tile in LDS; u[128] accumulators in VGPRs;
// Q rows read at wave-uniform addresses (scalar-load friendly).
// ---------------------------------------------------------------------------
__global__ __launch_bounds__(256) void quad_kernel(const float* __restrict__ x,
                                                   const float* __restrict__ Q,
                                                   float* __restrict__ out) {
  __shared__ float xs[NC][264];     // 263 used (256 t + 7 halo), pad to 264
  int b = blockIdx.x;
  int t0 = blockIdx.y * 256;
  const float* xb = x + (size_t)b * NC * LIN;
  int tid = threadIdx.x;
  for (int c = 0; c < NC; ++c) {
    for (int o = tid; o < 263; o += 256) {
      int g = t0 + o;
      xs[c][o] = (g < LIN) ? xb[c * LIN + g] : 0.0f;
    }
  }
  __syncthreads();

  float u[DD];
  #pragma unroll
  for (int i = 0; i < DD; ++i) u[i] = 0.0f;

  // u = Q^T v  (== Q v, symmetric); Q address depends only on j,i -> uniform
  for (int j = 0; j < DD; ++j) {
    float vj = xs[j >> 3][tid + (j & 7)];
    const float* qrow = Q + j * DD;
    #pragma unroll
    for (int i = 0; i < DD; ++i) u[i] = fmaf(qrow[i], vj, u[i]);
  }

  float dot = 0.0f, nrm = 0.0f;
  #pragma unroll
  for (int i = 0; i < DD; ++i) {
    float vi = xs[i >> 3][tid + (i & 7)];
    dot = fmaf(vi, u[i], dot);
    nrm = fmaf(vi, vi, nrm);
  }
  int t = t0 + tid;
  if (t < LOUT) out[(size_t)b * LOUT + t] = dot / (nrm + 1e-12f);
}

// ---------------------------------------------------------------------------

extern "C" void kernel_launch(void* const* d_in, const int* in_sizes, int n_in,
                              void* d_out, int out_size, void* d_ws, size_t ws_size,
                              hipStream_t stream) {
  const float* x     = (const float*)d_in[0];   // (16,16,4096) f32
  const float* E     = (const float*)d_in[1];   // (512,512)    f32
  const float* theta = (const float*)d_in[2];   // (3,9)        f32
  float* out = (float*)d_out;                   // (16,1,1,4089) f32

  float* B = (float*)d_ws;                      // 512*128
  float* C = B + QDIM * DD;                     // 512*128
  float* Q = C + QDIM * DD;                     // 128*128
  // total ws use: (2*65536 + 16384) * 4 = 576 KB

  init_B<<<QDIM * DD / 256, 256, 0, stream>>>(B);
  for (int l = 0; l < 3; ++l) {
    ry_kernel<<<DD, 256, 0, stream>>>(B, theta, l);
    mm_kernel<<<QDIM, 128, 0, stream>>>(E, B, C);
    float* tmp = B; B = C; C = tmp;
  }
  // after 3 swaps, A lives in B
  formq_kernel<<<DD, 128, 0, stream>>>(B, Q);

  quad_kernel<<<dim3(NB, 16), 256, 0, stream>>>(x, Q, out);
}